// Round 9
// baseline (214.294 us; speedup 1.0000x reference)
//
#include <hip/hip_runtime.h>

#define LN_EPS 1e-5f

typedef float v4f __attribute__((ext_vector_type(4)));

constexpr int BLOCK = 512;            // 8 waves
constexpr int RPT   = 8;              // rows per thread
constexpr int RPB   = BLOCK * RPT;    // 4096 rows per block

__global__ __launch_bounds__(BLOCK) void ln_linear_softmax_kernel(
    const v4f*   __restrict__ x,     // [n] rows of 4 floats
    const float* __restrict__ W,     // [4,3] row-major
    const float* __restrict__ gamma, // [4]
    const float* __restrict__ beta,  // [4]
    float*       __restrict__ out,   // [n,3] flat
    int n)
{
    const int  tid  = threadIdx.x;
    const long base = (long)blockIdx.x * RPB;
    const bool full = (base + RPB <= (long)n);

    const v4f g = *(const v4f*)gamma;
    const v4f b = *(const v4f*)beta;
    const v4f* W4 = (const v4f*)W;
    const v4f w0 = W4[0]; // W00 W01 W02 W10
    const v4f w1 = W4[1]; // W11 W12 W20 W21
    const v4f w2 = W4[2]; // W22 W30 W31 W32

    if (full) {
        // 8 unguarded back-to-back NT loads: 8 KB contiguous read burst
        // per wave (RPT=8 retest WITHOUT the R5 LDS-occupancy confound —
        // no LDS in this structure, so the only cost is ~32 VGPRs).
        v4f v[RPT];
        #pragma unroll
        for (int k = 0; k < RPT; ++k)
            v[k] = __builtin_nontemporal_load(&x[base + tid + k * BLOCK]);

        // Direct strided NT stores — no LDS, no barrier. Within a wave the
        // 3 stores/row fully cover each 768 B output span; CDNA L2 merges
        // partial-line writes via byte masks (verified R8: no write
        // amplification, tied with the LDS-repack version).
        #pragma unroll
        for (int k = 0; k < RPT; ++k) {
            const long row = base + tid + (long)k * BLOCK;
            v4f q = v[k];

            float mu = (q.x + q.y + q.z + q.w) * 0.25f;
            float dx = q.x - mu, dy = q.y - mu, dz = q.z - mu, dw = q.w - mu;
            float var = (dx*dx + dy*dy + dz*dz + dw*dw) * 0.25f;
            float rs  = rsqrtf(var + LN_EPS);

            float h0 = dx * rs * g.x + b.x;
            float h1 = dy * rs * g.y + b.y;
            float h2 = dz * rs * g.z + b.z;
            float h3 = dw * rs * g.w + b.w;

            float l0 = h0*w0.x + h1*w0.w + h2*w1.z + h3*w2.y;
            float l1 = h0*w0.y + h1*w1.x + h2*w1.w + h3*w2.z;
            float l2 = h0*w0.z + h1*w1.y + h2*w2.x + h3*w2.w;

            float m   = fmaxf(l0, fmaxf(l1, l2));
            float e0  = __expf(l0 - m);
            float e1  = __expf(l1 - m);
            float e2  = __expf(l2 - m);
            float inv = 1.0f / (e0 + e1 + e2);

            __builtin_nontemporal_store(e0 * inv, &out[row*3 + 0]);
            __builtin_nontemporal_store(e1 * inv, &out[row*3 + 1]);
            __builtin_nontemporal_store(e2 * inv, &out[row*3 + 2]);
        }
    } else {
        // Tail block (never hit for the bench shape): per-row scalar path.
        for (int k = 0; k < RPT; ++k) {
            const long row = base + tid + (long)k * BLOCK;
            if (row < n) {
                v4f q = __builtin_nontemporal_load(&x[row]);

                float mu = (q.x + q.y + q.z + q.w) * 0.25f;
                float dx = q.x - mu, dy = q.y - mu, dz = q.z - mu, dw = q.w - mu;
                float var = (dx*dx + dy*dy + dz*dz + dw*dw) * 0.25f;
                float rs  = rsqrtf(var + LN_EPS);

                float h0 = dx * rs * g.x + b.x;
                float h1 = dy * rs * g.y + b.y;
                float h2 = dz * rs * g.z + b.z;
                float h3 = dw * rs * g.w + b.w;

                float l0 = h0*w0.x + h1*w0.w + h2*w1.z + h3*w2.y;
                float l1 = h0*w0.y + h1*w1.x + h2*w1.w + h3*w2.z;
                float l2 = h0*w0.z + h1*w1.y + h2*w2.x + h3*w2.w;

                float m   = fmaxf(l0, fmaxf(l1, l2));
                float e0  = __expf(l0 - m);
                float e1  = __expf(l1 - m);
                float e2  = __expf(l2 - m);
                float inv = 1.0f / (e0 + e1 + e2);

                out[row*3 + 0] = e0 * inv;
                out[row*3 + 1] = e1 * inv;
                out[row*3 + 2] = e2 * inv;
            }
        }
    }
}

extern "C" void kernel_launch(void* const* d_in, const int* in_sizes, int n_in,
                              void* d_out, int out_size, void* d_ws, size_t ws_size,
                              hipStream_t stream) {
    const float* x     = (const float*)d_in[0];
    const float* W     = (const float*)d_in[1];
    const float* gamma = (const float*)d_in[2];
    const float* beta  = (const float*)d_in[3];
    float* out = (float*)d_out;

    int n = in_sizes[0] / 4;                 // number of rows (8,388,608)
    int grid = (n + RPB - 1) / RPB;          // 2048 blocks
    ln_linear_softmax_kernel<<<grid, BLOCK, 0, stream>>>(
        (const v4f*)x, W, gamma, beta, out, n);
}